// Round 1
// baseline (1050.521 us; speedup 1.0000x reference)
//
#include <hip/hip_runtime.h>
#include <hip/hip_bf16.h>
#include <math.h>

// Problem constants (B=2, T=2048, C=1024, H=16, D=64)
#define T_SEQ 2048
#define CDIM  1024
#define HEADS 16
#define DHEAD 64
#define BATCH 2
#define M_ROWS (BATCH * T_SEQ)  // 4096

// ---------------------------------------------------------------------------
// Kernel 1: RoPE cos/sin table  [T][32] each
// ---------------------------------------------------------------------------
__global__ void rope_table_kernel(float* __restrict__ cosT, float* __restrict__ sinT) {
    int idx = blockIdx.x * blockDim.x + threadIdx.x;
    if (idx >= T_SEQ * 32) return;
    int t = idx >> 5;
    int i = idx & 31;
    float expo = (2.0f * (float)i) / 64.0f;
    float inv = powf(10000.0f, -expo);
    float a = (float)t * inv;
    cosT[idx] = cosf(a);
    sinT[idx] = sinf(a);
}

// ---------------------------------------------------------------------------
// Kernel 2/4: fp32 GEMM, 128x128 tile, BK=16, 256 threads, 8x8 micro-tile.
// EPI=0: QKV epilogue (RoPE on q,k; scatter to [B,H,T,D] Q/K/V buffers)
// EPI=1: bias add, plain [M][N] store
// ---------------------------------------------------------------------------
template <int EPI>
__global__ __launch_bounds__(256)
void gemm128(const float* __restrict__ A, const float* __restrict__ Bm,
             int N, int K,
             const float* __restrict__ bias, float* __restrict__ out,
             float* __restrict__ qOut, float* __restrict__ kOut, float* __restrict__ vOut,
             const float* __restrict__ cosT, const float* __restrict__ sinT) {
    __shared__ float As[16][128];  // [k][m] (transposed A tile)
    __shared__ float Bs[16][128];  // [k][n]

    const int tid = threadIdx.x;
    const int m0 = blockIdx.y * 128;
    const int n0 = blockIdx.x * 128;
    const int tr = tid >> 4;       // 0..15
    const int tc = tid & 15;       // 0..15

    float acc[8][8];
#pragma unroll
    for (int i = 0; i < 8; i++)
#pragma unroll
        for (int j = 0; j < 8; j++) acc[i][j] = 0.f;

    // staging assignments
    const int arow = tid >> 2;        // 0..63
    const int ac4  = (tid & 3) << 2;  // 0,4,8,12
    const int brow = tid >> 5;        // 0..7
    const int bc4  = (tid & 31) << 2; // 0..124

    const float* Aptr0 = A + (size_t)(m0 + arow) * K + ac4;
    const float* Aptr1 = Aptr0 + (size_t)64 * K;
    const float* Bptr0 = Bm + (size_t)brow * N + n0 + bc4;
    const float* Bptr1 = Bptr0 + (size_t)8 * N;

    for (int k0 = 0; k0 < K; k0 += 16) {
        float4 a0 = *(const float4*)(Aptr0 + k0);
        float4 a1 = *(const float4*)(Aptr1 + k0);
        float4 b0 = *(const float4*)(Bptr0 + (size_t)k0 * N);
        float4 b1 = *(const float4*)(Bptr1 + (size_t)k0 * N);
        __syncthreads();  // previous iteration's reads complete
        As[ac4 + 0][arow] = a0.x; As[ac4 + 1][arow] = a0.y;
        As[ac4 + 2][arow] = a0.z; As[ac4 + 3][arow] = a0.w;
        As[ac4 + 0][arow + 64] = a1.x; As[ac4 + 1][arow + 64] = a1.y;
        As[ac4 + 2][arow + 64] = a1.z; As[ac4 + 3][arow + 64] = a1.w;
        *(float4*)&Bs[brow][bc4] = b0;
        *(float4*)&Bs[brow + 8][bc4] = b1;
        __syncthreads();
#pragma unroll
        for (int kk = 0; kk < 16; kk++) {
            float4 xa0 = *(const float4*)&As[kk][tr << 2];
            float4 xa1 = *(const float4*)&As[kk][64 + (tr << 2)];
            float4 xb0 = *(const float4*)&Bs[kk][tc << 2];
            float4 xb1 = *(const float4*)&Bs[kk][64 + (tc << 2)];
            float am[8] = {xa0.x, xa0.y, xa0.z, xa0.w, xa1.x, xa1.y, xa1.z, xa1.w};
            float bn[8] = {xb0.x, xb0.y, xb0.z, xb0.w, xb1.x, xb1.y, xb1.z, xb1.w};
#pragma unroll
            for (int r = 0; r < 8; r++)
#pragma unroll
                for (int c = 0; c < 8; c++) acc[r][c] = fmaf(am[r], bn[c], acc[r][c]);
        }
    }

    if (EPI == 0) {
        // QKV epilogue: n in [0,3072); sec 0=q 1=k 2=v; RoPE on q,k.
#pragma unroll
        for (int rg = 0; rg < 2; rg++)
#pragma unroll
            for (int rr = 0; rr < 4; rr++) {
                int m = m0 + rg * 64 + (tr << 2) + rr;
                int b = m >> 11, t = m & 2047;
#pragma unroll
                for (int cg = 0; cg < 2; cg++) {
                    int n = n0 + cg * 64 + (tc << 2);
                    int sec = n >> 10;
                    int cc = n & 1023;
                    int h = cc >> 6, d = cc & 63;
                    float v0 = acc[rg * 4 + rr][cg * 4 + 0];
                    float v1 = acc[rg * 4 + rr][cg * 4 + 1];
                    float v2 = acc[rg * 4 + rr][cg * 4 + 2];
                    float v3 = acc[rg * 4 + rr][cg * 4 + 3];
                    if (sec < 2) {
                        int i0 = (d >> 1);
                        float c0 = cosT[t * 32 + i0],     s0 = sinT[t * 32 + i0];
                        float c1 = cosT[t * 32 + i0 + 1], s1 = sinT[t * 32 + i0 + 1];
                        float e0 = v0 * c0 - v1 * s0, o0 = v0 * s0 + v1 * c0;
                        float e1 = v2 * c1 - v3 * s1, o1 = v2 * s1 + v3 * c1;
                        v0 = e0; v1 = o0; v2 = e1; v3 = o1;
                    }
                    float* dst = (sec == 0) ? qOut : ((sec == 1) ? kOut : vOut);
                    size_t off = (((size_t)((b * 16 + h) * 2048 + t)) << 6) + d;
                    *(float4*)&dst[off] = make_float4(v0, v1, v2, v3);
                }
            }
    } else {
        // proj epilogue: + bias, store [M][N]
#pragma unroll
        for (int rg = 0; rg < 2; rg++)
#pragma unroll
            for (int rr = 0; rr < 4; rr++) {
                int m = m0 + rg * 64 + (tr << 2) + rr;
#pragma unroll
                for (int cg = 0; cg < 2; cg++) {
                    int n = n0 + cg * 64 + (tc << 2);
                    float4 bv = *(const float4*)&bias[n];
                    float4 o;
                    o.x = acc[rg * 4 + rr][cg * 4 + 0] + bv.x;
                    o.y = acc[rg * 4 + rr][cg * 4 + 1] + bv.y;
                    o.z = acc[rg * 4 + rr][cg * 4 + 2] + bv.z;
                    o.w = acc[rg * 4 + rr][cg * 4 + 3] + bv.w;
                    *(float4*)&out[(size_t)m * N + n] = o;
                }
            }
    }
}

// ---------------------------------------------------------------------------
// Kernel 3: flash attention, fp32. One block = 64 q-rows of one (b,h).
// 64x64 S tiles, 4x4 micro, online softmax, causal.
// LDS: Qt (q^T, prescaled 1/8), KtPs (K^T aliased with P^T), Vs. 48 KiB.
// ---------------------------------------------------------------------------
__global__ __launch_bounds__(256)
void attn64(const float* __restrict__ Q, const float* __restrict__ K,
            const float* __restrict__ V, float* __restrict__ Y) {
    __shared__ float Qt[64][64];    // [d][r]
    __shared__ float KtPs[64][64];  // as K^T: [d][j]; later as P^T: [j][r]
    __shared__ float Vs[64][64];    // [j][d]

    const int tid = threadIdx.x;
    const int qi = gridDim.x - 1 - blockIdx.x;  // big-work blocks first
    const int bh = blockIdx.y;
    const int b = bh >> 4, h = bh & 15;
    const int q0 = qi << 6;
    const float* Qb = Q + ((size_t)bh << 17);
    const float* Kb = K + ((size_t)bh << 17);
    const float* Vb = V + ((size_t)bh << 17);

    const int lrow = tid >> 2;        // 0..63
    const int lc4  = (tid & 3) << 2;  // 0,4,8,12
    const int tr = tid >> 4, tc = tid & 15;

    // Stage Q transposed, with 1/sqrt(D)=0.125 folded in.
#pragma unroll
    for (int g = 0; g < 4; g++) {
        int d = lc4 + (g << 4);
        float4 qv = *(const float4*)&Qb[(size_t)(q0 + lrow) * 64 + d];
        Qt[d + 0][lrow] = qv.x * 0.125f;
        Qt[d + 1][lrow] = qv.y * 0.125f;
        Qt[d + 2][lrow] = qv.z * 0.125f;
        Qt[d + 3][lrow] = qv.w * 0.125f;
    }

    float m_r[4], l_r[4], O[4][4];
#pragma unroll
    for (int r = 0; r < 4; r++) {
        m_r[r] = -INFINITY; l_r[r] = 0.f;
#pragma unroll
        for (int c = 0; c < 4; c++) O[r][c] = 0.f;
    }

    for (int kt = 0; kt <= qi; kt++) {
        const int k0 = kt << 6;
        __syncthreads();  // prev PV reads of KtPs/Vs done (also covers Qt stage, iter 0)
#pragma unroll
        for (int g = 0; g < 4; g++) {
            int d = lc4 + (g << 4);
            float4 kv = *(const float4*)&Kb[(size_t)(k0 + lrow) * 64 + d];
            KtPs[d + 0][lrow] = kv.x; KtPs[d + 1][lrow] = kv.y;
            KtPs[d + 2][lrow] = kv.z; KtPs[d + 3][lrow] = kv.w;
            float4 vv = *(const float4*)&Vb[(size_t)(k0 + lrow) * 64 + d];
            *(float4*)&Vs[lrow][d] = vv;
        }
        __syncthreads();

        // S = (Q*scale) K^T  — 4x4 per thread
        float s[4][4];
#pragma unroll
        for (int r = 0; r < 4; r++)
#pragma unroll
            for (int c = 0; c < 4; c++) s[r][c] = 0.f;
#pragma unroll
        for (int d = 0; d < 64; d++) {
            float4 qa = *(const float4*)&Qt[d][tr << 2];
            float4 ka = *(const float4*)&KtPs[d][tc << 2];
            float qm[4] = {qa.x, qa.y, qa.z, qa.w};
            float kn[4] = {ka.x, ka.y, ka.z, ka.w};
#pragma unroll
            for (int r = 0; r < 4; r++)
#pragma unroll
                for (int c = 0; c < 4; c++) s[r][c] = fmaf(qm[r], kn[c], s[r][c]);
        }
        if (kt == qi) {  // causal mask on diagonal tile
#pragma unroll
            for (int r = 0; r < 4; r++)
#pragma unroll
                for (int c = 0; c < 4; c++)
                    if (k0 + (tc << 2) + c > q0 + (tr << 2) + r) s[r][c] = -1e30f;
        }
        __syncthreads();  // all K^T reads done; KtPs may be rewritten as P^T

        // online softmax (row stats across the 16 lanes sharing tr)
        float pv[4][4];
#pragma unroll
        for (int r = 0; r < 4; r++) {
            float lm = fmaxf(fmaxf(s[r][0], s[r][1]), fmaxf(s[r][2], s[r][3]));
#pragma unroll
            for (int w = 1; w < 16; w <<= 1) lm = fmaxf(lm, __shfl_xor(lm, w));
            float mn = fmaxf(m_r[r], lm);
            float alpha = expf(m_r[r] - mn);  // expf(-inf)=0 on first tile
            float sum = 0.f;
#pragma unroll
            for (int c = 0; c < 4; c++) {
                float p = expf(s[r][c] - mn);
                pv[r][c] = p; sum += p;
            }
#pragma unroll
            for (int w = 1; w < 16; w <<= 1) sum += __shfl_xor(sum, w);
            l_r[r] = l_r[r] * alpha + sum;
            m_r[r] = mn;
#pragma unroll
            for (int c = 0; c < 4; c++) O[r][c] *= alpha;
        }
        // write P^T into KtPs: [j][r]
#pragma unroll
        for (int c = 0; c < 4; c++) {
            float4 pw = make_float4(pv[0][c], pv[1][c], pv[2][c], pv[3][c]);
            *(float4*)&KtPs[(tc << 2) + c][tr << 2] = pw;
        }
        __syncthreads();

        // O += P V — thread owns (r, d) 4x4
#pragma unroll
        for (int j = 0; j < 64; j++) {
            float4 pa = *(const float4*)&KtPs[j][tr << 2];
            float4 va = *(const float4*)&Vs[j][tc << 2];
            float pm[4] = {pa.x, pa.y, pa.z, pa.w};
            float vn[4] = {va.x, va.y, va.z, va.w};
#pragma unroll
            for (int r = 0; r < 4; r++)
#pragma unroll
                for (int c = 0; c < 4; c++) O[r][c] = fmaf(pm[r], vn[c], O[r][c]);
        }
    }

    // finalize: divide by l, write y in [B,T,C] layout
#pragma unroll
    for (int r = 0; r < 4; r++) {
        float inv = 1.0f / l_r[r];
        int t = q0 + (tr << 2) + r;
        float4 o = make_float4(O[r][0] * inv, O[r][1] * inv, O[r][2] * inv, O[r][3] * inv);
        *(float4*)&Y[(size_t)(b * 2048 + t) * 1024 + h * 64 + (tc << 2)] = o;
    }
}

// ---------------------------------------------------------------------------
extern "C" void kernel_launch(void* const* d_in, const int* in_sizes, int n_in,
                              void* d_out, int out_size, void* d_ws, size_t ws_size,
                              hipStream_t stream) {
    const float* x      = (const float*)d_in[0];
    const float* w_qkv  = (const float*)d_in[1];
    const float* w_proj = (const float*)d_in[2];
    const float* b_proj = (const float*)d_in[3];
    float* out = (float*)d_out;

    float* ws = (float*)d_ws;
    const size_t SZ = (size_t)M_ROWS * CDIM;  // 4096*1024
    float* Qb   = ws;
    float* Kb   = Qb + SZ;
    float* Vb   = Kb + SZ;
    float* Yb   = Vb + SZ;
    float* cosT = Yb + SZ;
    float* sinT = cosT + (size_t)T_SEQ * 32;

    rope_table_kernel<<<dim3((T_SEQ * 32 + 255) / 256), dim3(256), 0, stream>>>(cosT, sinT);

    // qkv = x @ w_qkv, fused RoPE + scatter to [B,H,T,D]
    gemm128<0><<<dim3(24, 32), dim3(256), 0, stream>>>(
        x, w_qkv, 3 * CDIM, CDIM,
        nullptr, nullptr, Qb, Kb, Vb, cosT, sinT);

    // flash attention
    attn64<<<dim3(T_SEQ / 64, BATCH * HEADS), dim3(256), 0, stream>>>(Qb, Kb, Vb, Yb);

    // out = y @ w_proj + b_proj
    gemm128<1><<<dim3(8, 32), dim3(256), 0, stream>>>(
        Yb, w_proj, CDIM, CDIM,
        b_proj, out, nullptr, nullptr, nullptr, nullptr, nullptr);
}

// Round 2
// 288.329 us; speedup vs baseline: 3.6435x; 3.6435x over previous
//
#include <hip/hip_runtime.h>
#include <math.h>

#define T_SEQ 2048
#define CDIM  1024
#define HEADS 16
#define DHEAD 64
#define BATCH 2
#define M_ROWS 4096

typedef unsigned short u16;
typedef unsigned int u32;
typedef __attribute__((ext_vector_type(8))) short bf16x8;
typedef __attribute__((ext_vector_type(4))) float f32x4;

__device__ inline u16 f2bf(float f) {
    u32 u = __builtin_bit_cast(u32, f);
    u32 r = (u + 0x7fffu + ((u >> 16) & 1u)) >> 16;  // RNE
    return (u16)r;
}

__device__ inline void gload16(const void* g, void* l) {
    __builtin_amdgcn_global_load_lds(
        (const __attribute__((address_space(1))) void*)g,
        (__attribute__((address_space(3))) void*)l, 16, 0, 0);
}

// ---------------------------------------------------------------------------
// RoPE cos/sin table [T][32]
// ---------------------------------------------------------------------------
__global__ void rope_table_kernel(float* __restrict__ cosT, float* __restrict__ sinT) {
    int idx = blockIdx.x * blockDim.x + threadIdx.x;
    if (idx >= T_SEQ * 32) return;
    int t = idx >> 5;
    int i = idx & 31;
    float expo = (2.0f * (float)i) / 64.0f;
    float inv = powf(10000.0f, -expo);
    float a = (float)t * inv;
    cosT[idx] = cosf(a);
    sinT[idx] = sinf(a);
}

// ---------------------------------------------------------------------------
// fp32 -> bf16 elementwise (8 elems/thread)
// ---------------------------------------------------------------------------
__global__ __launch_bounds__(256)
void conv_bf16(const float* __restrict__ in, u16* __restrict__ out, int n8) {
    int i = blockIdx.x * blockDim.x + threadIdx.x;
    if (i >= n8) return;
    const float4* p = (const float4*)(in + (size_t)i * 8);
    float4 a = p[0], b = p[1];
    uint4 o;
    o.x = (u32)f2bf(a.x) | ((u32)f2bf(a.y) << 16);
    o.y = (u32)f2bf(a.z) | ((u32)f2bf(a.w) << 16);
    o.z = (u32)f2bf(b.x) | ((u32)f2bf(b.y) << 16);
    o.w = (u32)f2bf(b.z) | ((u32)f2bf(b.w) << 16);
    *(uint4*)(out + (size_t)i * 8) = o;
}

// ---------------------------------------------------------------------------
// fp32 [K][N] -> bf16 [N][K] (weight transpose+convert), 64x64 tiles
// ---------------------------------------------------------------------------
__global__ __launch_bounds__(256)
void convT64(const float* __restrict__ in, u16* __restrict__ out, int K, int N) {
    __shared__ float Ls[64][65];
    const int tid = threadIdx.x;
    const int k0 = blockIdx.y << 6, n0 = blockIdx.x << 6;
    const int r0 = tid >> 4, c4 = (tid & 15) << 2;
#pragma unroll
    for (int p = 0; p < 4; p++) {
        int r = r0 + (p << 4);
        float4 v = *(const float4*)&in[(size_t)(k0 + r) * N + n0 + c4];
        Ls[r][c4 + 0] = v.x; Ls[r][c4 + 1] = v.y;
        Ls[r][c4 + 2] = v.z; Ls[r][c4 + 3] = v.w;
    }
    __syncthreads();
    const int n = tid >> 2, kq = (tid & 3) << 4;
    u32 pk[8];
#pragma unroll
    for (int j = 0; j < 8; j++) {
        float lo = Ls[kq + 2 * j][n], hi = Ls[kq + 2 * j + 1][n];
        pk[j] = (u32)f2bf(lo) | ((u32)f2bf(hi) << 16);
    }
    u32* dst = (u32*)&out[(size_t)(n0 + n) * K + k0 + kq];
    ((uint4*)dst)[0] = make_uint4(pk[0], pk[1], pk[2], pk[3]);
    ((uint4*)dst)[1] = make_uint4(pk[4], pk[5], pk[6], pk[7]);
}

// ---------------------------------------------------------------------------
// bf16 V [bh][2048][64] -> Vt [bh][64][2048], 64x64 tiles
// ---------------------------------------------------------------------------
__global__ __launch_bounds__(256)
void transposeV(const u16* __restrict__ in, u16* __restrict__ out) {
    __shared__ u16 Ls[64][72];  // 144B row stride (16B-aligned)
    const int tid = threadIdx.x;
    const int bh = blockIdx.y;
    const int t0 = blockIdx.x << 6;
    const u16* src = in + ((size_t)bh << 17) + ((size_t)t0 << 6);
#pragma unroll
    for (int p = 0; p < 2; p++) {
        int L = tid + (p << 8);
        int t = L >> 3, c = L & 7;
        uint4 v = *(const uint4*)&src[(size_t)t * 64 + (c << 3)];
        *(uint4*)&Ls[t][c << 3] = v;
    }
    __syncthreads();
    const int d = tid >> 2, tq = (tid & 3) << 4;
    u32 pk[8];
#pragma unroll
    for (int j = 0; j < 8; j++) {
        u16 lo = Ls[tq + 2 * j][d], hi = Ls[tq + 2 * j + 1][d];
        pk[j] = (u32)lo | ((u32)hi << 16);
    }
    u16* dst = out + ((size_t)bh << 17) + ((size_t)d << 11) + t0 + tq;
    ((uint4*)dst)[0] = make_uint4(pk[0], pk[1], pk[2], pk[3]);
    ((uint4*)dst)[1] = make_uint4(pk[4], pk[5], pk[6], pk[7]);
}

// ---------------------------------------------------------------------------
// bf16 MFMA GEMM, 128x128 tile, BK=32, 4 waves (2x2), 16x16x32 frags.
// A [M][K] bf16, Bt [N][K] bf16 (pre-transposed), fp32 accum.
// EPI=0: RoPE on q,k; scatter Q/K/V bf16 [B,H,T,D].  EPI=1: +bias, fp32 out.
// ---------------------------------------------------------------------------
template <int EPI>
__global__ __launch_bounds__(256)
void gemm_bf16(const u16* __restrict__ A, const u16* __restrict__ Bt,
               int N, int K,
               const float* __restrict__ bias, float* __restrict__ outF,
               u16* __restrict__ qOut, u16* __restrict__ kOut, u16* __restrict__ vOut,
               const float* __restrict__ cosT, const float* __restrict__ sinT) {
    __shared__ u16 Alds[128 * 32];
    __shared__ u16 Blds[128 * 32];
    const int tid = threadIdx.x;
    const int lane = tid & 63;
    const int w = tid >> 6;
    const int wr = w >> 1, wc = w & 1;
    const int g = lane >> 4, l15 = lane & 15;
    const int m0 = blockIdx.y * 128, n0 = blockIdx.x * 128;

    f32x4 acc[4][4];
#pragma unroll
    for (int m = 0; m < 4; m++)
#pragma unroll
        for (int n = 0; n < 4; n++)
#pragma unroll
            for (int e = 0; e < 4; e++) acc[m][n][e] = 0.f;

    int aoff[4], boff[4];
#pragma unroll
    for (int m = 0; m < 4; m++) {
        aoff[m] = ((wr << 6) + (m << 4) + l15) * 64 + (g << 4);
        boff[m] = ((wc << 6) + (m << 4) + l15) * 64 + (g << 4);
    }
    // staging: 512 chunks each for A,B; thread handles L=tid, tid+256
    const int rowA0 = tid >> 2, kk0 = (tid & 3) << 3;

    for (int k0 = 0; k0 < K; k0 += 32) {
        __syncthreads();
#pragma unroll
        for (int p = 0; p < 2; p++) {
            int L = tid + (p << 8);
            int row = rowA0 + (p << 6);
            gload16(A + (size_t)(m0 + row) * K + k0 + kk0, (u16*)Alds + (size_t)L * 8);
            gload16(Bt + (size_t)(n0 + row) * K + k0 + kk0, (u16*)Blds + (size_t)L * 8);
        }
        __syncthreads();
        bf16x8 af[4], bfr[4];
#pragma unroll
        for (int m = 0; m < 4; m++) af[m] = *(const bf16x8*)((const char*)Alds + aoff[m]);
#pragma unroll
        for (int n = 0; n < 4; n++) bfr[n] = *(const bf16x8*)((const char*)Blds + boff[n]);
#pragma unroll
        for (int m = 0; m < 4; m++)
#pragma unroll
            for (int n = 0; n < 4; n++)
                acc[m][n] = __builtin_amdgcn_mfma_f32_16x16x32_bf16(af[m], bfr[n], acc[m][n], 0, 0, 0);
    }

    if (EPI == 0) {
        const int sec = n0 >> 10;  // uniform per block (BN=128 divides 1024)
#pragma unroll
        for (int m = 0; m < 4; m++) {
#pragma unroll
            for (int j = 0; j < 4; j++) {
                int t = m0 + (wr << 6) + (m << 4) + (g << 2) + j;
                int b = t >> 11, tt = t & 2047;
#pragma unroll
                for (int n = 0; n < 4; n++) {
                    int cc = (n0 + (wc << 6) + (n << 4) + l15) & 1023;
                    int h = cc >> 6, d = cc & 63;
                    float val = acc[m][n][j];
                    float o = val;
                    if (sec < 2) {
                        float partner = __shfl_xor(val, 1);
                        int i0 = d >> 1;
                        float c = cosT[tt * 32 + i0], s = sinT[tt * 32 + i0];
                        o = ((d & 1) == 0) ? (val * c - partner * s)
                                           : (partner * s + val * c);
                    }
                    size_t off = (((size_t)((b * 16 + h) * 2048 + tt)) << 6) + d;
                    u16* dst = (sec == 0) ? qOut : ((sec == 1) ? kOut : vOut);
                    dst[off] = f2bf(o);
                }
            }
        }
    } else {
#pragma unroll
        for (int m = 0; m < 4; m++) {
#pragma unroll
            for (int j = 0; j < 4; j++) {
                int t = m0 + (wr << 6) + (m << 4) + (g << 2) + j;
#pragma unroll
                for (int n = 0; n < 4; n++) {
                    int col = n0 + (wc << 6) + (n << 4) + l15;
                    outF[(size_t)t * N + col] = acc[m][n][j] + bias[col];
                }
            }
        }
    }
}

// ---------------------------------------------------------------------------
// Flash attention, bf16 MFMA. Block = (bh, 64 q-rows). 4 waves x 16 q-rows.
// LDS tiles XOR-swizzled at 16B-chunk granularity: chunk' = chunk ^ (row&7).
// ---------------------------------------------------------------------------
__global__ __launch_bounds__(256)
void attn_mfma(const u16* __restrict__ Qg, const u16* __restrict__ Kg,
               const u16* __restrict__ Vtg, u16* __restrict__ Yg) {
    __shared__ u16 Qs[64 * 64];
    __shared__ u16 Ks[64 * 64];
    __shared__ u16 Vts[64 * 64];
    __shared__ u16 Ps[4 * 16 * 64];

    const int tid = threadIdx.x;
    const int lane = tid & 63;
    const int w = tid >> 6;
    const int g = lane >> 4, l15 = lane & 15;
    const int qi = gridDim.x - 1 - blockIdx.x;  // big-work blocks first
    const int bh = blockIdx.y;
    const int q0 = qi << 6;

    const u16* Qbase = Qg + ((size_t)bh << 17);
    const u16* Kbase = Kg + ((size_t)bh << 17);
    const u16* Vtbase = Vtg + ((size_t)bh << 17);  // [64 d][2048 t]

    // stage Q once (swizzled source -> linear LDS)
#pragma unroll
    for (int p = 0; p < 2; p++) {
        int L = tid + (p << 8);
        int row = L >> 3, c = L & 7;
        int cg = (c ^ (row & 7)) << 3;
        gload16(Qbase + ((size_t)(q0 + row) << 6) + cg, (u16*)Qs + (size_t)L * 8);
    }

    // fragment LDS byte offsets (kv-invariant)
    const int qrow = (w << 4) + l15;
    int qoff[2], poff[2], rcoff[2][4];
#pragma unroll
    for (int s = 0; s < 2; s++) {
        int ch = (s << 2) + g;
        qoff[s] = qrow * 128 + ((ch ^ (qrow & 7)) << 4);
        poff[s] = (w << 11) + l15 * 128 + ((ch ^ (l15 & 7)) << 4);
#pragma unroll
        for (int n = 0; n < 4; n++) {
            int row = (n << 4) + l15;
            rcoff[s][n] = row * 128 + ((ch ^ (row & 7)) << 4);
        }
    }

    f32x4 Of[4];
    float mrun[4], lrun[4];
#pragma unroll
    for (int n = 0; n < 4; n++)
#pragma unroll
        for (int e = 0; e < 4; e++) Of[n][e] = 0.f;
#pragma unroll
    for (int j = 0; j < 4; j++) { mrun[j] = -INFINITY; lrun[j] = 0.f; }

    bf16x8 qa2[2];

    for (int kt = 0; kt <= qi; kt++) {
        const int k0 = kt << 6;
        __syncthreads();  // (a) prior PV reads of Ks/Vts done
#pragma unroll
        for (int p = 0; p < 2; p++) {
            int L = tid + (p << 8);
            int row = L >> 3, c = L & 7;
            int cg = (c ^ (row & 7)) << 3;
            gload16(Kbase + ((size_t)(k0 + row) << 6) + cg, (u16*)Ks + (size_t)L * 8);
            gload16(Vtbase + ((size_t)row << 11) + k0 + cg, (u16*)Vts + (size_t)L * 8);
        }
        __syncthreads();  // (b) staging visible (also Q on first iter)

        if (kt == 0) {
            qa2[0] = *(const bf16x8*)((const char*)Qs + qoff[0]);
            qa2[1] = *(const bf16x8*)((const char*)Qs + qoff[1]);
        }

        // S = Q K^T (pre-scale folded later via softmax? no: fold 1/8 into exp arg)
        f32x4 sf[4];
#pragma unroll
        for (int n = 0; n < 4; n++)
#pragma unroll
            for (int e = 0; e < 4; e++) sf[n][e] = 0.f;
#pragma unroll
        for (int s = 0; s < 2; s++)
#pragma unroll
            for (int n = 0; n < 4; n++) {
                bf16x8 kb = *(const bf16x8*)((const char*)Ks + rcoff[s][n]);
                sf[n] = __builtin_amdgcn_mfma_f32_16x16x32_bf16(qa2[s], kb, sf[n], 0, 0, 0);
            }
        // scale 1/sqrt(64) and causal mask
#pragma unroll
        for (int n = 0; n < 4; n++)
#pragma unroll
            for (int j = 0; j < 4; j++) sf[n][j] *= 0.125f;
        if (kt == qi) {
#pragma unroll
            for (int n = 0; n < 4; n++)
#pragma unroll
                for (int j = 0; j < 4; j++)
                    if ((n << 4) + l15 > (w << 4) + (g << 2) + j) sf[n][j] = -1e30f;
        }

        // online softmax (rows replicated across the 16 lanes of each g-group)
        float mx[4];
#pragma unroll
        for (int j = 0; j < 4; j++)
            mx[j] = fmaxf(fmaxf(sf[0][j], sf[1][j]), fmaxf(sf[2][j], sf[3][j]));
#pragma unroll
        for (int dd = 1; dd < 16; dd <<= 1)
#pragma unroll
            for (int j = 0; j < 4; j++) mx[j] = fmaxf(mx[j], __shfl_xor(mx[j], dd));
        float alpha[4];
#pragma unroll
        for (int j = 0; j < 4; j++) {
            float mn = fmaxf(mrun[j], mx[j]);
            alpha[j] = __expf(mrun[j] - mn);
            mrun[j] = mn;
        }
        float pbuf[4][4];
        float rs[4] = {0.f, 0.f, 0.f, 0.f};
#pragma unroll
        for (int n = 0; n < 4; n++)
#pragma unroll
            for (int j = 0; j < 4; j++) {
                float p = __expf(sf[n][j] - mrun[j]);
                pbuf[n][j] = p;
                rs[j] += p;
            }
#pragma unroll
        for (int dd = 1; dd < 16; dd <<= 1)
#pragma unroll
            for (int j = 0; j < 4; j++) rs[j] += __shfl_xor(rs[j], dd);
#pragma unroll
        for (int j = 0; j < 4; j++) lrun[j] = lrun[j] * alpha[j] + rs[j];
#pragma unroll
        for (int n = 0; n < 4; n++)
#pragma unroll
            for (int j = 0; j < 4; j++) Of[n][j] *= alpha[j];

        // write P (bf16) to wave-private swizzled LDS
#pragma unroll
        for (int n = 0; n < 4; n++)
#pragma unroll
            for (int j = 0; j < 4; j++) {
                int kv = (n << 4) + l15;
                int q16 = (g << 2) + j;
                int idx = (w << 10) + (q16 << 6) + (((kv >> 3) ^ (q16 & 7)) << 3) + (kv & 7);
                Ps[idx] = f2bf(pbuf[n][j]);
            }
        asm volatile("s_waitcnt lgkmcnt(0)" ::: "memory");
        __builtin_amdgcn_sched_barrier(0);

        // O += P V
#pragma unroll
        for (int s = 0; s < 2; s++) {
            bf16x8 pa = *(const bf16x8*)((const char*)Ps + poff[s]);
#pragma unroll
            for (int n = 0; n < 4; n++) {
                bf16x8 vb = *(const bf16x8*)((const char*)Vts + rcoff[s][n]);
                Of[n] = __builtin_amdgcn_mfma_f32_16x16x32_bf16(pa, vb, Of[n], 0, 0, 0);
            }
        }
    }

    // finalize + store Y bf16 [B][T][C]
    const int b = bh >> 4, h = bh & 15;
#pragma unroll
    for (int j = 0; j < 4; j++) {
        float inv = 1.0f / lrun[j];
        int t = q0 + (w << 4) + (g << 2) + j;
#pragma unroll
        for (int n = 0; n < 4; n++) {
            int d = (n << 4) + l15;
            Yg[((size_t)(b * 2048 + t) << 10) + (h << 6) + d] = f2bf(Of[n][j] * inv);
        }
    }
}

// ---------------------------------------------------------------------------
extern "C" void kernel_launch(void* const* d_in, const int* in_sizes, int n_in,
                              void* d_out, int out_size, void* d_ws, size_t ws_size,
                              hipStream_t stream) {
    const float* x      = (const float*)d_in[0];
    const float* w_qkv  = (const float*)d_in[1];
    const float* w_proj = (const float*)d_in[2];
    const float* b_proj = (const float*)d_in[3];
    float* out = (float*)d_out;

    const size_t SZ = (size_t)M_ROWS * CDIM;  // 4M elems
    char* ws = (char*)d_ws;
    u16* xb     = (u16*)ws;                ws += SZ * 2;
    u16* wqkvT  = (u16*)ws;                ws += (size_t)3 * CDIM * CDIM * 2;
    u16* wprojT = (u16*)ws;                ws += (size_t)CDIM * CDIM * 2;
    u16* Qb     = (u16*)ws;                ws += SZ * 2;
    u16* Kb     = (u16*)ws;                ws += SZ * 2;
    u16* Vb     = (u16*)ws;                ws += SZ * 2;
    u16* Vt     = (u16*)ws;                ws += SZ * 2;
    u16* Yb     = (u16*)ws;                ws += SZ * 2;
    float* cosT = (float*)ws;              ws += (size_t)T_SEQ * 32 * 4;
    float* sinT = (float*)ws;              ws += (size_t)T_SEQ * 32 * 4;

    rope_table_kernel<<<dim3(256), dim3(256), 0, stream>>>(cosT, sinT);
    conv_bf16<<<dim3(2048), dim3(256), 0, stream>>>(x, xb, (int)(SZ / 8));
    convT64<<<dim3(48, 16), dim3(256), 0, stream>>>(w_qkv, wqkvT, CDIM, 3 * CDIM);
    convT64<<<dim3(16, 16), dim3(256), 0, stream>>>(w_proj, wprojT, CDIM, CDIM);

    gemm_bf16<0><<<dim3(24, 32), dim3(256), 0, stream>>>(
        xb, wqkvT, 3 * CDIM, CDIM, nullptr, nullptr, Qb, Kb, Vb, cosT, sinT);

    transposeV<<<dim3(32, 32), dim3(256), 0, stream>>>(Vb, Vt);

    attn_mfma<<<dim3(32, 32), dim3(256), 0, stream>>>(Qb, Kb, Vt, Yb);

    gemm_bf16<1><<<dim3(8, 32), dim3(256), 0, stream>>>(
        Yb, wprojT, CDIM, CDIM, b_proj, out, nullptr, nullptr, nullptr, nullptr, nullptr);
}

// Round 3
// 228.905 us; speedup vs baseline: 4.5893x; 1.2596x over previous
//
#include <hip/hip_runtime.h>
#include <math.h>

#define T_SEQ 2048
#define CDIM  1024
#define HEADS 16
#define DHEAD 64
#define BATCH 2
#define M_ROWS 4096
#define QSCALE 0.18033688011112042f  // 0.125 * log2(e)

typedef unsigned short u16;
typedef unsigned int u32;
typedef __attribute__((ext_vector_type(8))) short bf16x8;
typedef __attribute__((ext_vector_type(4))) float f32x4;

__device__ inline u16 f2bf(float f) {
    u32 u = __builtin_bit_cast(u32, f);
    u32 r = (u + 0x7fffu + ((u >> 16) & 1u)) >> 16;  // RNE
    return (u16)r;
}

__device__ inline u32 cvtpk(float lo, float hi) {
    u32 r;
    asm("v_cvt_pk_bf16_f32 %0, %1, %2" : "=v"(r) : "v"(lo), "v"(hi));
    return r;
}

__device__ inline float fexp2(float x) {
#if __has_builtin(__builtin_amdgcn_exp2f)
    return __builtin_amdgcn_exp2f(x);
#else
    float r; asm("v_exp_f32 %0, %1" : "=v"(r) : "v"(x)); return r;
#endif
}

__device__ inline void gload16(const void* g, void* l) {
    __builtin_amdgcn_global_load_lds(
        (const __attribute__((address_space(1))) void*)g,
        (__attribute__((address_space(3))) void*)l, 16, 0, 0);
}

// ---------------------------------------------------------------------------
// RoPE cos/sin table [T][32]
// ---------------------------------------------------------------------------
__global__ void rope_table_kernel(float* __restrict__ cosT, float* __restrict__ sinT) {
    int idx = blockIdx.x * blockDim.x + threadIdx.x;
    if (idx >= T_SEQ * 32) return;
    int t = idx >> 5;
    int i = idx & 31;
    float expo = (2.0f * (float)i) / 64.0f;
    float inv = powf(10000.0f, -expo);
    float a = (float)t * inv;
    cosT[idx] = cosf(a);
    sinT[idx] = sinf(a);
}

// ---------------------------------------------------------------------------
// fp32 -> bf16 elementwise (8 elems/thread)
// ---------------------------------------------------------------------------
__global__ __launch_bounds__(256)
void conv_bf16(const float* __restrict__ in, u16* __restrict__ out, int n8) {
    int i = blockIdx.x * blockDim.x + threadIdx.x;
    if (i >= n8) return;
    const float4* p = (const float4*)(in + (size_t)i * 8);
    float4 a = p[0], b = p[1];
    uint4 o;
    o.x = (u32)f2bf(a.x) | ((u32)f2bf(a.y) << 16);
    o.y = (u32)f2bf(a.z) | ((u32)f2bf(a.w) << 16);
    o.z = (u32)f2bf(b.x) | ((u32)f2bf(b.y) << 16);
    o.w = (u32)f2bf(b.z) | ((u32)f2bf(b.w) << 16);
    *(uint4*)(out + (size_t)i * 8) = o;
}

// ---------------------------------------------------------------------------
// fp32 [K][N] -> bf16 [N][K] (weight transpose+convert), 64x64 tiles
// ---------------------------------------------------------------------------
__global__ __launch_bounds__(256)
void convT64(const float* __restrict__ in, u16* __restrict__ out, int K, int N) {
    __shared__ float Ls[64][65];
    const int tid = threadIdx.x;
    const int k0 = blockIdx.y << 6, n0 = blockIdx.x << 6;
    const int r0 = tid >> 4, c4 = (tid & 15) << 2;
#pragma unroll
    for (int p = 0; p < 4; p++) {
        int r = r0 + (p << 4);
        float4 v = *(const float4*)&in[(size_t)(k0 + r) * N + n0 + c4];
        Ls[r][c4 + 0] = v.x; Ls[r][c4 + 1] = v.y;
        Ls[r][c4 + 2] = v.z; Ls[r][c4 + 3] = v.w;
    }
    __syncthreads();
    const int n = tid >> 2, kq = (tid & 3) << 4;
    u32 pk[8];
#pragma unroll
    for (int j = 0; j < 8; j++) {
        float lo = Ls[kq + 2 * j][n], hi = Ls[kq + 2 * j + 1][n];
        pk[j] = (u32)f2bf(lo) | ((u32)f2bf(hi) << 16);
    }
    u32* dst = (u32*)&out[(size_t)(n0 + n) * K + k0 + kq];
    ((uint4*)dst)[0] = make_uint4(pk[0], pk[1], pk[2], pk[3]);
    ((uint4*)dst)[1] = make_uint4(pk[4], pk[5], pk[6], pk[7]);
}

// ---------------------------------------------------------------------------
// bf16 V [bh][2048][64] -> Vt [bh][64][2048], 64x64 tiles
// ---------------------------------------------------------------------------
__global__ __launch_bounds__(256)
void transposeV(const u16* __restrict__ in, u16* __restrict__ out) {
    __shared__ u16 Ls[64][72];
    const int tid = threadIdx.x;
    const int bh = blockIdx.y;
    const int t0 = blockIdx.x << 6;
    const u16* src = in + ((size_t)bh << 17) + ((size_t)t0 << 6);
#pragma unroll
    for (int p = 0; p < 2; p++) {
        int L = tid + (p << 8);
        int t = L >> 3, c = L & 7;
        uint4 v = *(const uint4*)&src[(size_t)t * 64 + (c << 3)];
        *(uint4*)&Ls[t][c << 3] = v;
    }
    __syncthreads();
    const int d = tid >> 2, tq = (tid & 3) << 4;
    u32 pk[8];
#pragma unroll
    for (int j = 0; j < 8; j++) {
        u16 lo = Ls[tq + 2 * j][d], hi = Ls[tq + 2 * j + 1][d];
        pk[j] = (u32)lo | ((u32)hi << 16);
    }
    u16* dst = out + ((size_t)bh << 17) + ((size_t)d << 11) + t0 + tq;
    ((uint4*)dst)[0] = make_uint4(pk[0], pk[1], pk[2], pk[3]);
    ((uint4*)dst)[1] = make_uint4(pk[4], pk[5], pk[6], pk[7]);
}

// ---------------------------------------------------------------------------
// bf16 MFMA GEMM, 128x128 tile, BK=32, dbl-buffered LDS + counted vmcnt.
// EPI=0: RoPE on q,k (+QSCALE on q); scatter Q/K/V bf16. EPI=1: +bias fp32.
// ---------------------------------------------------------------------------
template <int EPI>
__global__ __launch_bounds__(256)
void gemm_bf16(const u16* __restrict__ A, const u16* __restrict__ Bt,
               int N, int K,
               const float* __restrict__ bias, float* __restrict__ outF,
               u16* __restrict__ qOut, u16* __restrict__ kOut, u16* __restrict__ vOut,
               const float* __restrict__ cosT, const float* __restrict__ sinT) {
    __shared__ u16 Alds[2][128 * 32];
    __shared__ u16 Blds[2][128 * 32];
    const int tid = threadIdx.x;
    const int lane = tid & 63;
    const int w = tid >> 6;
    const int wr = w >> 1, wc = w & 1;
    const int g = lane >> 4, l15 = lane & 15;
    const int m0 = blockIdx.y * 128, n0 = blockIdx.x * 128;

    f32x4 acc[4][4];
#pragma unroll
    for (int m = 0; m < 4; m++)
#pragma unroll
        for (int n = 0; n < 4; n++)
#pragma unroll
            for (int e = 0; e < 4; e++) acc[m][n][e] = 0.f;

    int aoff[4], boff[4];
#pragma unroll
    for (int m = 0; m < 4; m++) {
        aoff[m] = ((wr << 6) + (m << 4) + l15) * 64 + (g << 4);
        boff[m] = ((wc << 6) + (m << 4) + l15) * 64 + (g << 4);
    }
    const int rowA0 = tid >> 2, kk0 = (tid & 3) << 3;

#define GSTAGE(BUF, K0)                                                          \
    {                                                                            \
        _Pragma("unroll") for (int pq = 0; pq < 2; pq++) {                       \
            int L = tid + (pq << 8);                                             \
            int row = rowA0 + (pq << 6);                                         \
            gload16(A + (size_t)(m0 + row) * K + (K0) + kk0, &Alds[BUF][0] + L * 8); \
            gload16(Bt + (size_t)(n0 + row) * K + (K0) + kk0, &Blds[BUF][0] + L * 8); \
        }                                                                        \
    }

    GSTAGE(0, 0);
    const int nt = K >> 5;
    int cur = 0;
    for (int t = 0; t < nt; t++) {
        if (t + 1 < nt) {
            GSTAGE(cur ^ 1, ((t + 1) << 5));
            asm volatile("s_waitcnt vmcnt(4)" ::: "memory");
        } else {
            asm volatile("s_waitcnt vmcnt(0)" ::: "memory");
        }
        __builtin_amdgcn_s_barrier();
        asm volatile("" ::: "memory");
        bf16x8 af[4], bfr[4];
#pragma unroll
        for (int m = 0; m < 4; m++) af[m] = *(const bf16x8*)((const char*)&Alds[cur][0] + aoff[m]);
#pragma unroll
        for (int n = 0; n < 4; n++) bfr[n] = *(const bf16x8*)((const char*)&Blds[cur][0] + boff[n]);
#pragma unroll
        for (int m = 0; m < 4; m++)
#pragma unroll
            for (int n = 0; n < 4; n++)
                acc[m][n] = __builtin_amdgcn_mfma_f32_16x16x32_bf16(af[m], bfr[n], acc[m][n], 0, 0, 0);
        asm volatile("" ::: "memory");
        __builtin_amdgcn_s_barrier();
        cur ^= 1;
    }
#undef GSTAGE

    if (EPI == 0) {
        const int sec = n0 >> 10;  // uniform per block
#pragma unroll
        for (int m = 0; m < 4; m++) {
#pragma unroll
            for (int j = 0; j < 4; j++) {
                int t = m0 + (wr << 6) + (m << 4) + (g << 2) + j;
                int b = t >> 11, tt = t & 2047;
#pragma unroll
                for (int n = 0; n < 4; n++) {
                    int cc = (n0 + (wc << 6) + (n << 4) + l15) & 1023;
                    int h = cc >> 6, d = cc & 63;
                    float val = acc[m][n][j];
                    float o = val;
                    if (sec < 2) {
                        float partner = __shfl_xor(val, 1);
                        int i0 = d >> 1;
                        float c = cosT[tt * 32 + i0], s = sinT[tt * 32 + i0];
                        o = ((d & 1) == 0) ? (val * c - partner * s)
                                           : (partner * s + val * c);
                        if (sec == 0) o *= QSCALE;
                    }
                    size_t off = (((size_t)((b * 16 + h) * 2048 + tt)) << 6) + d;
                    u16* dst = (sec == 0) ? qOut : ((sec == 1) ? kOut : vOut);
                    dst[off] = f2bf(o);
                }
            }
        }
    } else {
#pragma unroll
        for (int m = 0; m < 4; m++) {
#pragma unroll
            for (int j = 0; j < 4; j++) {
                int t = m0 + (wr << 6) + (m << 4) + (g << 2) + j;
#pragma unroll
                for (int n = 0; n < 4; n++) {
                    int col = n0 + (wc << 6) + (n << 4) + l15;
                    outF[(size_t)t * N + col] = acc[m][n][j] + bias[col];
                }
            }
        }
    }
}

// ---------------------------------------------------------------------------
// Flash attention, bf16 MFMA, wedge-paired blocks (tiles p and 31-p),
// double-buffered K/V with counted vmcnt, exp2-domain softmax, defer-max.
// ---------------------------------------------------------------------------
__device__ __forceinline__ void kv_stage(const u16* Kbase, const u16* Vtbase,
                                         u16* Kl, u16* Vl, int tid, int kt) {
#pragma unroll
    for (int pp = 0; pp < 2; pp++) {
        int L = tid + (pp << 8);
        int row = L >> 3, c = L & 7;
        int cg = (c ^ (row & 7)) << 3;
        gload16(Kbase + (((size_t)(kt << 6) + row) << 6) + cg, Kl + L * 8);
        gload16(Vtbase + ((size_t)row << 11) + (kt << 6) + cg, Vl + L * 8);
    }
}

__device__ __forceinline__ void attn_step(
    const bf16x8 (&qf)[2], f32x4 (&OF)[4], float (&MR)[4], float (&LR)[4],
    const char* Kl, const char* Vl, bool diag,
    int w, int g, int l15, const int (&rc)[2][4],
    u16* const (&pw)[4], const u16* prd) {
    f32x4 sf[4];
#pragma unroll
    for (int n = 0; n < 4; n++)
#pragma unroll
        for (int e = 0; e < 4; e++) sf[n][e] = 0.f;
#pragma unroll
    for (int s = 0; s < 2; s++)
#pragma unroll
        for (int n = 0; n < 4; n++) {
            bf16x8 kb = *(const bf16x8*)(Kl + rc[s][n]);
            sf[n] = __builtin_amdgcn_mfma_f32_16x16x32_bf16(qf[s], kb, sf[n], 0, 0, 0);
        }
    if (diag) {
#pragma unroll
        for (int n = 0; n < 4; n++)
#pragma unroll
            for (int j = 0; j < 4; j++)
                if ((n << 4) + l15 > (w << 4) + (g << 2) + j) sf[n][j] = -1e30f;
    }
    float mx[4];
#pragma unroll
    for (int j = 0; j < 4; j++)
        mx[j] = fmaxf(fmaxf(sf[0][j], sf[1][j]), fmaxf(sf[2][j], sf[3][j]));
#pragma unroll
    for (int dd = 1; dd < 16; dd <<= 1)
#pragma unroll
        for (int j = 0; j < 4; j++) mx[j] = fmaxf(mx[j], __shfl_xor(mx[j], dd));
    float dmax = fmaxf(fmaxf(mx[0] - MR[0], mx[1] - MR[1]),
                       fmaxf(mx[2] - MR[2], mx[3] - MR[3]));
    if (__ballot(dmax > 10.f) != 0ull) {  // defer-max: rescale only when needed
#pragma unroll
        for (int j = 0; j < 4; j++) {
            float nm = fmaxf(MR[j], mx[j]);
            float al = fexp2(MR[j] - nm);
            MR[j] = nm;
            LR[j] *= al;
#pragma unroll
            for (int n = 0; n < 4; n++) OF[n][j] *= al;
        }
    }
    float rs[4] = {0.f, 0.f, 0.f, 0.f};
#pragma unroll
    for (int n = 0; n < 4; n++)
#pragma unroll
        for (int j = 0; j < 4; j++) {
            float pv = fexp2(sf[n][j] - MR[j]);
            sf[n][j] = pv;
            rs[j] += pv;
        }
#pragma unroll
    for (int dd = 1; dd < 16; dd <<= 1)
#pragma unroll
        for (int j = 0; j < 4; j++) rs[j] += __shfl_xor(rs[j], dd);
#pragma unroll
    for (int j = 0; j < 4; j++) LR[j] += rs[j];
#pragma unroll
    for (int n = 0; n < 4; n++) {
        u32 p01 = cvtpk(sf[n][0], sf[n][1]);
        u32 p23 = cvtpk(sf[n][2], sf[n][3]);
        pw[0][n * 16] = (u16)p01; pw[1][n * 16] = (u16)(p01 >> 16);
        pw[2][n * 16] = (u16)p23; pw[3][n * 16] = (u16)(p23 >> 16);
    }
    asm volatile("s_waitcnt lgkmcnt(0)" ::: "memory");
    __builtin_amdgcn_sched_barrier(0);
#pragma unroll
    for (int s = 0; s < 2; s++) {
        bf16x8 pa = *(const bf16x8*)(prd + (s << 5) + (g << 3));
#pragma unroll
        for (int n = 0; n < 4; n++) {
            bf16x8 vb = *(const bf16x8*)(Vl + rc[s][n]);
            OF[n] = __builtin_amdgcn_mfma_f32_16x16x32_bf16(pa, vb, OF[n], 0, 0, 0);
        }
    }
}

__device__ __forceinline__ void attn_store(
    const f32x4 (&OF)[4], const float (&LR)[4], u16* Yg, int b, int h,
    int q0, int w, int g, int l15) {
#pragma unroll
    for (int j = 0; j < 4; j++) {
        float inv = 1.0f / LR[j];
        int t = q0 + (w << 4) + (g << 2) + j;
#pragma unroll
        for (int n = 0; n < 4; n++) {
            int d = (n << 4) + l15;
            Yg[((size_t)(b * 2048 + t) << 10) + (h << 6) + d] = f2bf(OF[n][j] * inv);
        }
    }
}

__global__ __launch_bounds__(256)
void attn_mfma(const u16* __restrict__ Qg, const u16* __restrict__ Kg,
               const u16* __restrict__ Vtg, u16* __restrict__ Yg) {
    __shared__ u16 Ks[2][64 * 64];
    __shared__ u16 Vts[2][64 * 64];
    __shared__ u16 Ps[4][16][72];

    const int tid = threadIdx.x;
    const int lane = tid & 63;
    const int w = tid >> 6;
    const int g = lane >> 4, l15 = lane & 15;
    const int p = blockIdx.x;  // 0..15
    const int bh = blockIdx.y;
    const int b = bh >> 4, h = bh & 15;
    const int qtA = p, qtB = 31 - p;
    const int q0A = qtA << 6, q0B = qtB << 6;

    const u16* Qbase = Qg + ((size_t)bh << 17);
    const u16* Kbase = Kg + ((size_t)bh << 17);
    const u16* Vtbase = Vtg + ((size_t)bh << 17);

    // Q fragments direct global->register (A-frag: row=l15, k=s*32+g*8)
    const int qrowL = (w << 4) + l15;
    bf16x8 qfA[2], qfB[2];
#pragma unroll
    for (int s = 0; s < 2; s++) {
        qfA[s] = *(const bf16x8*)(Qbase + ((size_t)(q0A + qrowL) << 6) + (s << 5) + (g << 3));
        qfB[s] = *(const bf16x8*)(Qbase + ((size_t)(q0B + qrowL) << 6) + (s << 5) + (g << 3));
    }

    int rc[2][4];
#pragma unroll
    for (int s = 0; s < 2; s++)
#pragma unroll
        for (int n = 0; n < 4; n++) {
            int row = (n << 4) + l15;
            rc[s][n] = row * 128 + ((((s << 2) + g) ^ (row & 7)) << 4);
        }
    u16* pw[4];
#pragma unroll
    for (int j = 0; j < 4; j++) pw[j] = &Ps[w][(g << 2) + j][l15];
    const u16* prd = &Ps[w][l15][0];

    f32x4 OA[4], OB[4];
    float mA[4], lA[4], mB[4], lB[4];
#pragma unroll
    for (int n = 0; n < 4; n++)
#pragma unroll
        for (int e = 0; e < 4; e++) { OA[n][e] = 0.f; OB[n][e] = 0.f; }
#pragma unroll
    for (int j = 0; j < 4; j++) { mA[j] = -INFINITY; lA[j] = 0.f; mB[j] = -INFINITY; lB[j] = 0.f; }

    kv_stage(Kbase, Vtbase, &Ks[0][0], &Vts[0][0], tid, 0);
    int cur = 0;

    // Phase A: tile qtA (kt = 0..qtA); last iter prefetches B's kv0
    for (int kt = 0; kt <= qtA; kt++) {
        int kvn = (kt < qtA) ? kt + 1 : 0;
        kv_stage(Kbase, Vtbase, &Ks[cur ^ 1][0], &Vts[cur ^ 1][0], tid, kvn);
        asm volatile("s_waitcnt vmcnt(4)" ::: "memory");
        __builtin_amdgcn_s_barrier();
        asm volatile("" ::: "memory");
        attn_step(qfA, OA, mA, lA, (const char*)&Ks[cur][0], (const char*)&Vts[cur][0],
                  kt == qtA, w, g, l15, rc, pw, prd);
        asm volatile("" ::: "memory");
        __builtin_amdgcn_s_barrier();
        cur ^= 1;
    }
    attn_store(OA, lA, Yg, b, h, q0A, w, g, l15);

    // Phase B: tile qtB (kt = 0..qtB)
    for (int kt = 0; kt <= qtB; kt++) {
        if (kt < qtB) {
            kv_stage(Kbase, Vtbase, &Ks[cur ^ 1][0], &Vts[cur ^ 1][0], tid, kt + 1);
            asm volatile("s_waitcnt vmcnt(4)" ::: "memory");
        } else {
            asm volatile("s_waitcnt vmcnt(0)" ::: "memory");
        }
        __builtin_amdgcn_s_barrier();
        asm volatile("" ::: "memory");
        attn_step(qfB, OB, mB, lB, (const char*)&Ks[cur][0], (const char*)&Vts[cur][0],
                  kt == qtB, w, g, l15, rc, pw, prd);
        asm volatile("" ::: "memory");
        __builtin_amdgcn_s_barrier();
        cur ^= 1;
    }
    attn_store(OB, lB, Yg, b, h, q0B, w, g, l15);
}

// ---------------------------------------------------------------------------
extern "C" void kernel_launch(void* const* d_in, const int* in_sizes, int n_in,
                              void* d_out, int out_size, void* d_ws, size_t ws_size,
                              hipStream_t stream) {
    const float* x      = (const float*)d_in[0];
    const float* w_qkv  = (const float*)d_in[1];
    const float* w_proj = (const float*)d_in[2];
    const float* b_proj = (const float*)d_in[3];
    float* out = (float*)d_out;

    const size_t SZ = (size_t)M_ROWS * CDIM;
    char* ws = (char*)d_ws;
    u16* xb     = (u16*)ws;                ws += SZ * 2;
    u16* wqkvT  = (u16*)ws;                ws += (size_t)3 * CDIM * CDIM * 2;
    u16* wprojT = (u16*)ws;                ws += (size_t)CDIM * CDIM * 2;
    u16* Qb     = (u16*)ws;                ws += SZ * 2;
    u16* Kb     = (u16*)ws;                ws += SZ * 2;
    u16* Vb     = (u16*)ws;                ws += SZ * 2;
    u16* Vt     = (u16*)ws;                ws += SZ * 2;
    u16* Yb     = (u16*)ws;                ws += SZ * 2;
    float* cosT = (float*)ws;              ws += (size_t)T_SEQ * 32 * 4;
    float* sinT = (float*)ws;              ws += (size_t)T_SEQ * 32 * 4;

    rope_table_kernel<<<dim3(256), dim3(256), 0, stream>>>(cosT, sinT);
    conv_bf16<<<dim3(2048), dim3(256), 0, stream>>>(x, xb, (int)(SZ / 8));
    convT64<<<dim3(48, 16), dim3(256), 0, stream>>>(w_qkv, wqkvT, CDIM, 3 * CDIM);
    convT64<<<dim3(16, 16), dim3(256), 0, stream>>>(w_proj, wprojT, CDIM, CDIM);

    gemm_bf16<0><<<dim3(24, 32), dim3(256), 0, stream>>>(
        xb, wqkvT, 3 * CDIM, CDIM, nullptr, nullptr, Qb, Kb, Vb, cosT, sinT);

    transposeV<<<dim3(32, 32), dim3(256), 0, stream>>>(Vb, Vt);

    attn_mfma<<<dim3(16, 32), dim3(256), 0, stream>>>(Qb, Kb, Vt, Yb);

    gemm_bf16<1><<<dim3(8, 32), dim3(256), 0, stream>>>(
        Yb, wprojT, CDIM, CDIM, b_proj, out, nullptr, nullptr, nullptr, nullptr, nullptr);
}